// Round 1
// baseline (216.319 us; speedup 1.0000x reference)
//
#include <hip/hip_runtime.h>
#include <hip/hip_bf16.h>
#include <stdint.h>

// Problem constants (B=2, S=2048, IN=4096, OUT=4096)
#define MDIM 4096   // B*S
#define NDIM 4096   // OUT
#define KDIM 4096   // IN

typedef __attribute__((ext_vector_type(4))) float  f32x4;
typedef __attribute__((ext_vector_type(8))) short  bf16x8;
typedef __attribute__((ext_vector_type(4))) float  fx4;
typedef __attribute__((ext_vector_type(4))) int    ix4;
typedef __attribute__((ext_vector_type(8))) unsigned short usx8;

__device__ static inline unsigned short f32_to_bf16_rne(float f) {
  union { float f; unsigned int u; } v; v.f = f;
  unsigned int u = v.u;
  u += 0x7fffu + ((u >> 16) & 1u);
  return (unsigned short)(u >> 16);
}

__device__ static inline void gload_lds16(const unsigned short* g, unsigned short* l) {
  __builtin_amdgcn_global_load_lds((const __attribute__((address_space(1))) void*)g,
                                   (__attribute__((address_space(3))) void*)l,
                                   16, 0, 0);
}

// ---------------- conversion kernels (ws fast path) ----------------

__global__ void cvt_x_kernel(const float* __restrict__ in,
                             unsigned short* __restrict__ out, int n8) {
  int idx = blockIdx.x * blockDim.x + threadIdx.x;
  int stride = gridDim.x * blockDim.x;
  for (int i = idx; i < n8; i += stride) {
    const fx4* p = reinterpret_cast<const fx4*>(in) + (size_t)i * 2;
    fx4 a = p[0], b = p[1];
    usx8 r;
    r[0] = f32_to_bf16_rne(a[0]); r[1] = f32_to_bf16_rne(a[1]);
    r[2] = f32_to_bf16_rne(a[2]); r[3] = f32_to_bf16_rne(a[3]);
    r[4] = f32_to_bf16_rne(b[0]); r[5] = f32_to_bf16_rne(b[1]);
    r[6] = f32_to_bf16_rne(b[2]); r[7] = f32_to_bf16_rne(b[3]);
    reinterpret_cast<usx8*>(out)[i] = r;
  }
}

__global__ void cvt_w_kernel(const int* __restrict__ in,
                             unsigned short* __restrict__ out, int n8) {
  int idx = blockIdx.x * blockDim.x + threadIdx.x;
  int stride = gridDim.x * blockDim.x;
  for (int i = idx; i < n8; i += stride) {
    const ix4* p = reinterpret_cast<const ix4*>(in) + (size_t)i * 2;
    ix4 a = p[0], b = p[1];
    usx8 r;
    r[0] = f32_to_bf16_rne((float)a[0]); r[1] = f32_to_bf16_rne((float)a[1]);
    r[2] = f32_to_bf16_rne((float)a[2]); r[3] = f32_to_bf16_rne((float)a[3]);
    r[4] = f32_to_bf16_rne((float)b[0]); r[5] = f32_to_bf16_rne((float)b[1]);
    r[6] = f32_to_bf16_rne((float)b[2]); r[7] = f32_to_bf16_rne((float)b[3]);
    reinterpret_cast<usx8*>(out)[i] = r;
  }
}

// ---------------- shared GEMM pieces ----------------
// Tile: BM=BN=128, BK=32. 256 threads = 4 waves, each wave owns a 64x64
// quadrant (wr,wc), computing 4x4 fragments of mfma_f32_16x16x32_bf16.
// Fragment layout (gfx950, verified in learn_hip m89/m91):
//   A/B input: lane l holds row (l&15), k = 8*(l>>4)+j (contiguous bf16x8)
//   C/D: col = lane&15, row = (lane>>4)*4 + reg

__device__ static inline void mfma_step(const unsigned short* As,
                                        const unsigned short* Bs,
                                        f32x4 acc[4][4],
                                        int wr, int wc, int fr, int fq) {
  bf16x8 af[4], bfr[4];
  const unsigned short* ap = As + (wr * 64 + fr) * 32 + fq * 8;
  const unsigned short* bp = Bs + (wc * 64 + fr) * 32 + fq * 8;
#pragma unroll
  for (int i = 0; i < 4; ++i) {
    af[i]  = *reinterpret_cast<const bf16x8*>(ap + i * 512);  // 16 rows * 32
    bfr[i] = *reinterpret_cast<const bf16x8*>(bp + i * 512);
  }
#pragma unroll
  for (int im = 0; im < 4; ++im)
#pragma unroll
    for (int in_ = 0; in_ < 4; ++in_)
      acc[im][in_] = __builtin_amdgcn_mfma_f32_16x16x32_bf16(
          af[im], bfr[in_], acc[im][in_], 0, 0, 0);
}

__device__ static inline void epilogue(f32x4 acc[4][4],
                                       const float* __restrict__ scales,
                                       const float* __restrict__ bias,
                                       float* __restrict__ C,
                                       int bm, int bn, int wr, int wc,
                                       int fr, int fq) {
  const float inv127 = 1.0f / 127.0f;
#pragma unroll
  for (int in_ = 0; in_ < 4; ++in_) {
    int n = bn * 128 + wc * 64 + in_ * 16 + fr;
    float sc = scales[n] * inv127;
    float bz = bias[n];
#pragma unroll
    for (int im = 0; im < 4; ++im) {
      int m0 = bm * 128 + wr * 64 + im * 16 + fq * 4;
      float* cp = C + (size_t)m0 * NDIM + n;
#pragma unroll
      for (int r = 0; r < 4; ++r)
        cp[(size_t)r * NDIM] = acc[im][in_][r] * sc + bz;
    }
  }
}

// ---------------- fast path: pre-converted bf16 inputs ----------------

__global__ __launch_bounds__(256) void gemm_bt(
    const unsigned short* __restrict__ A,    // [M][K] bf16 bits
    const unsigned short* __restrict__ Bw,   // [N][K] bf16 bits
    const float* __restrict__ scales,
    const float* __restrict__ bias,
    float* __restrict__ C) {
  __shared__ unsigned short As[128 * 32];
  __shared__ unsigned short Bs[128 * 32];

  const int tid = threadIdx.x;
  const int wave = tid >> 6, lane = tid & 63;
  const int wr = wave >> 1, wc = wave & 1;
  const int fr = lane & 15, fq = lane >> 4;

  // XCD-aware swizzle over 1024 blocks (1024 % 8 == 0 -> simple form valid)
  int id = blockIdx.x;
  int swz = (id & 7) * 128 + (id >> 3);
  const int bm = swz >> 5, bn = swz & 31;

  // staging: chunk t covers row t>>2, k-offset (t&3)*8; chunk t+256 -> +64 rows
  const int r0 = tid >> 2;
  const int kc = (tid & 3) * 8;
  const size_t aBase = (size_t)(bm * 128 + r0) * KDIM + kc;
  const size_t bBase = (size_t)(bn * 128 + r0) * KDIM + kc;
  unsigned short* asDst0 = As + wave * 512;
  unsigned short* asDst1 = As + 2048 + wave * 512;
  unsigned short* bsDst0 = Bs + wave * 512;
  unsigned short* bsDst1 = Bs + 2048 + wave * 512;

  f32x4 acc[4][4] = {};

#pragma unroll 2
  for (int k0 = 0; k0 < KDIM; k0 += 32) {
    const unsigned short* ag = A + aBase + k0;
    const unsigned short* bg = Bw + bBase + k0;
    gload_lds16(ag, asDst0);
    gload_lds16(ag + (size_t)64 * KDIM, asDst1);
    gload_lds16(bg, bsDst0);
    gload_lds16(bg + (size_t)64 * KDIM, bsDst1);
    __syncthreads();   // compiler drains vmcnt before s_barrier
    mfma_step(As, Bs, acc, wr, wc, fr, fq);
    __syncthreads();
  }

  epilogue(acc, scales, bias, C, bm, bn, wr, wc, fr, fq);
}

// ---------------- fallback: fused conversion, reg staging ----------------

__global__ __launch_bounds__(256) void gemm_fused(
    const float* __restrict__ X,
    const int* __restrict__ W,
    const float* __restrict__ scales,
    const float* __restrict__ bias,
    float* __restrict__ C) {
  __shared__ unsigned short As[128 * 32];
  __shared__ unsigned short Bs[128 * 32];

  const int tid = threadIdx.x;
  const int wave = tid >> 6, lane = tid & 63;
  const int wr = wave >> 1, wc = wave & 1;
  const int fr = lane & 15, fq = lane >> 4;

  int id = blockIdx.x;
  int swz = (id & 7) * 128 + (id >> 3);
  const int bm = swz >> 5, bn = swz & 31;

  const int r0 = tid >> 2;
  const int kc = (tid & 3) * 8;
  const size_t aBase = (size_t)(bm * 128 + r0) * KDIM + kc;
  const size_t bBase = (size_t)(bn * 128 + r0) * KDIM + kc;

  f32x4 acc[4][4] = {};

  for (int k0 = 0; k0 < KDIM; k0 += 32) {
    const float* xp = X + aBase + k0;
    const int*   wp = W + bBase + k0;
    fx4 x0 = *(const fx4*)xp;
    fx4 x1 = *(const fx4*)(xp + 4);
    fx4 x2 = *(const fx4*)(xp + (size_t)64 * KDIM);
    fx4 x3 = *(const fx4*)(xp + (size_t)64 * KDIM + 4);
    ix4 w0 = *(const ix4*)wp;
    ix4 w1 = *(const ix4*)(wp + 4);
    ix4 w2 = *(const ix4*)(wp + (size_t)64 * KDIM);
    ix4 w3 = *(const ix4*)(wp + (size_t)64 * KDIM + 4);

    usx8 ca, cb, cc, cd;
#pragma unroll
    for (int j = 0; j < 4; ++j) {
      ca[j] = f32_to_bf16_rne(x0[j]);  ca[j + 4] = f32_to_bf16_rne(x1[j]);
      cb[j] = f32_to_bf16_rne(x2[j]);  cb[j + 4] = f32_to_bf16_rne(x3[j]);
      cc[j] = f32_to_bf16_rne((float)w0[j]); cc[j + 4] = f32_to_bf16_rne((float)w1[j]);
      cd[j] = f32_to_bf16_rne((float)w2[j]); cd[j + 4] = f32_to_bf16_rne((float)w3[j]);
    }

    __syncthreads();   // previous iteration's reads complete
    *reinterpret_cast<usx8*>(As + tid * 8)        = ca;
    *reinterpret_cast<usx8*>(As + 2048 + tid * 8) = cb;
    *reinterpret_cast<usx8*>(Bs + tid * 8)        = cc;
    *reinterpret_cast<usx8*>(Bs + 2048 + tid * 8) = cd;
    __syncthreads();
    mfma_step(As, Bs, acc, wr, wc, fr, fq);
  }

  epilogue(acc, scales, bias, C, bm, bn, wr, wc, fr, fq);
}

// ---------------- host launch ----------------

extern "C" void kernel_launch(void* const* d_in, const int* in_sizes, int n_in,
                              void* d_out, int out_size, void* d_ws, size_t ws_size,
                              hipStream_t stream) {
  const float* x      = (const float*)d_in[0];
  const int*   w8     = (const int*)d_in[1];
  const float* scales = (const float*)d_in[2];
  // d_in[3] = weight_fp : unused by the reference
  const float* bias   = (const float*)d_in[4];
  float* out = (float*)d_out;

  const size_t xb_elems = (size_t)MDIM * KDIM;
  const size_t wb_elems = (size_t)NDIM * KDIM;
  const size_t need = (xb_elems + wb_elems) * sizeof(unsigned short);

  if (ws_size >= need) {
    unsigned short* xb = (unsigned short*)d_ws;
    unsigned short* wb = xb + xb_elems;
    int n8 = (int)(xb_elems / 8);
    cvt_x_kernel<<<2048, 256, 0, stream>>>(x, xb, n8);
    cvt_w_kernel<<<2048, 256, 0, stream>>>(w8, wb, n8);
    gemm_bt<<<1024, 256, 0, stream>>>(xb, wb, scales, bias, out);
  } else {
    gemm_fused<<<1024, 256, 0, stream>>>(x, w8, scales, bias, out);
  }
}

// Round 2
// 162.667 us; speedup vs baseline: 1.3298x; 1.3298x over previous
//
#include <hip/hip_runtime.h>
#include <hip/hip_bf16.h>
#include <stdint.h>

// Problem constants (B=2, S=2048, IN=4096, OUT=4096)
#define MDIM 4096   // B*S
#define NDIM 4096   // OUT
#define KDIM 4096   // IN
#define NT   (KDIM / 64)   // 64 K-tiles of BK=64

typedef __attribute__((ext_vector_type(4))) float  f32x4;
typedef __attribute__((ext_vector_type(8))) short  bf16x8;
typedef __attribute__((ext_vector_type(4))) float  fx4;
typedef __attribute__((ext_vector_type(4))) int    ix4;
typedef __attribute__((ext_vector_type(8))) unsigned short usx8;

__device__ static inline unsigned short f32_to_bf16_rne(float f) {
  union { float f; unsigned int u; } v; v.f = f;
  unsigned int u = v.u;
  u += 0x7fffu + ((u >> 16) & 1u);
  return (unsigned short)(u >> 16);
}

__device__ static inline void gload_lds16(const unsigned short* g, unsigned short* l) {
  __builtin_amdgcn_global_load_lds((const __attribute__((address_space(1))) void*)g,
                                   (__attribute__((address_space(3))) void*)l,
                                   16, 0, 0);
}

// ---------------- conversion kernels ----------------

__global__ void cvt_x_kernel(const float* __restrict__ in,
                             unsigned short* __restrict__ out, int n8) {
  int idx = blockIdx.x * blockDim.x + threadIdx.x;
  int stride = gridDim.x * blockDim.x;
  for (int i = idx; i < n8; i += stride) {
    const fx4* p = reinterpret_cast<const fx4*>(in) + (size_t)i * 2;
    fx4 a = p[0], b = p[1];
    usx8 r;
    r[0] = f32_to_bf16_rne(a[0]); r[1] = f32_to_bf16_rne(a[1]);
    r[2] = f32_to_bf16_rne(a[2]); r[3] = f32_to_bf16_rne(a[3]);
    r[4] = f32_to_bf16_rne(b[0]); r[5] = f32_to_bf16_rne(b[1]);
    r[6] = f32_to_bf16_rne(b[2]); r[7] = f32_to_bf16_rne(b[3]);
    reinterpret_cast<usx8*>(out)[i] = r;
  }
}

__global__ void cvt_w_kernel(const int* __restrict__ in,
                             unsigned short* __restrict__ out, int n8) {
  int idx = blockIdx.x * blockDim.x + threadIdx.x;
  int stride = gridDim.x * blockDim.x;
  for (int i = idx; i < n8; i += stride) {
    const ix4* p = reinterpret_cast<const ix4*>(in) + (size_t)i * 2;
    ix4 a = p[0], b = p[1];
    usx8 r;
    r[0] = f32_to_bf16_rne((float)a[0]); r[1] = f32_to_bf16_rne((float)a[1]);
    r[2] = f32_to_bf16_rne((float)a[2]); r[3] = f32_to_bf16_rne((float)a[3]);
    r[4] = f32_to_bf16_rne((float)b[0]); r[5] = f32_to_bf16_rne((float)b[1]);
    r[6] = f32_to_bf16_rne((float)b[2]); r[7] = f32_to_bf16_rne((float)b[3]);
    reinterpret_cast<usx8*>(out)[i] = r;
  }
}

// ---------------- 256x256 8-phase GEMM (T1+T2+T3+T4+T5) ----------------
// 512 threads = 8 waves (WARPS_M=2 x WARPS_N=4). Per-wave output 128x64.
// BK=64, LDS = 2 dbuf x (256x64 A + 256x64 B) bf16 = 128 KiB.
// LDS swizzle: logical (row, slot q of 8x16B) stored at slot q^(row&7);
// gload_lds writes linearly with pre-swizzled per-lane GLOBAL source
// (k_slot = (l&7)^(l>>3)); ds_read applies the same XOR. 2-way residual
// conflict only (free).
// Staging schedule (safe by region-lifetime analysis; phase order
// P1=(mq0,nq0) P2=(mq0,nq1) P3=(mq1,nq0) P4=(mq1,nq1); A-half last read
// at P3, B-half at P2):
//   tile u: P1 stages (u+1)A0, P2 (u+1)A1, P3 (u+2)B0, P4 (u+2)B1
//   -> vmcnt(4) at tile end (2 half-tiles in flight, never 0 until drain)
// Prologue: t0{B0,B1,A0,A1} + t1{B0,B1}, vmcnt(4), barrier.

__global__ __launch_bounds__(512, 2) void gemm_8ph(
    const unsigned short* __restrict__ A,    // [M][K] bf16 bits
    const unsigned short* __restrict__ Bw,   // [N][K] bf16 bits
    const float* __restrict__ scales,
    const float* __restrict__ bias,
    float* __restrict__ C) {
  __shared__ unsigned short Ash[32768];   // 64 KiB: [2][256][64]
  __shared__ unsigned short Bsh[32768];   // 64 KiB

  const int tid = threadIdx.x;
  const int w   = tid >> 6;          // wave 0..7
  const int l   = tid & 63;
  const int wr  = w >> 2;            // 0..1 : M half
  const int wc  = w & 3;             // 0..3 : N quarter
  const int fr  = l & 15;            // fragment row
  const int fq  = l >> 4;            // fragment k-quarter / C row group

  // XCD-aware swizzle: 256 blocks, 256 % 8 == 0 -> simple bijective form
  const int id  = blockIdx.x;
  const int swz = (id & 7) * 32 + (id >> 3);
  const int bm  = swz >> 4, bn = swz & 15;

  const unsigned short* aorg = A  + (size_t)(bm * 256) * KDIM;
  const unsigned short* borg = Bw + (size_t)(bn * 256) * KDIM;

  // staging per-thread global offset (pre-swizzled source)
  const int lr = l >> 3;                 // row-in-octet 0..7
  const int ks = (l & 7) ^ lr;           // swizzled k-slot
  const size_t g_off = (size_t)(w * 16 + lr) * KDIM + (size_t)ks * 8;
  const int    s_off = w * 1024;         // lds elems (wave-uniform)

#define STAGE(isB, t, h) do {                                                   \
    const unsigned short* _g = ((isB) ? borg : aorg)                            \
        + (size_t)(h) * 128 * KDIM + (size_t)(t) * 64 + g_off;                  \
    unsigned short* _l = ((isB) ? Bsh : Ash)                                    \
        + (((t) & 1) * 16384 + (h) * 8192 + s_off);                             \
    gload_lds16(_g, _l);                                                        \
    gload_lds16(_g + 8 * KDIM, _l + 512);                                       \
  } while (0)

  // ds_read offsets (swizzled)
  const int arow = (wr * 128 + fr) * 64;
  const int brow = (wc * 64  + fr) * 64;
  const int q0 = ((fq)     ^ (fr & 7)) * 8;   // k-half 0 slot
  const int q1 = ((4 + fq) ^ (fr & 7)) * 8;   // k-half 1 slot

#define LDA(rb, qq) (*(const bf16x8*)(Ash + dOff + arow + (rb) * 1024 + (qq)))
#define LDB(nc, qq) (*(const bf16x8*)(Bsh + dOff + brow + (nc) * 1024 + (qq)))

  f32x4 acc[8][4] = {};

  // ---- prologue: 6 half-tiles, 12 loads/thread ----
  STAGE(1, 0, 0);  // t0 B0
  STAGE(1, 0, 1);  // t0 B1
  STAGE(0, 0, 0);  // t0 A0
  STAGE(0, 0, 1);  // t0 A1
  STAGE(1, 1, 0);  // t1 B0
  STAGE(1, 1, 1);  // t1 B1
  asm volatile("s_waitcnt vmcnt(4)" ::: "memory");   // t0 fully landed
  __builtin_amdgcn_s_barrier();

  for (int u = 0; u < NT; ++u) {
    const int dOff = (u & 1) * 16384;
    bf16x8 a0[4][2], a1[4][2], b0[2][2], b1[2][2];

    // ---- P1: mq0 x nq0 (12 ds_reads) ----
#pragma unroll
    for (int rb = 0; rb < 4; ++rb) { a0[rb][0] = LDA(rb, q0); a0[rb][1] = LDA(rb, q1); }
#pragma unroll
    for (int cb = 0; cb < 2; ++cb) { b0[cb][0] = LDB(cb, q0); b0[cb][1] = LDB(cb, q1); }
    if (u + 1 < NT) STAGE(0, u + 1, 0);          // (u+1) A0
    __builtin_amdgcn_s_barrier();
    asm volatile("s_waitcnt lgkmcnt(0)");
    __builtin_amdgcn_s_setprio(1);
#pragma unroll
    for (int rb = 0; rb < 4; ++rb)
#pragma unroll
      for (int cb = 0; cb < 2; ++cb) {
        acc[rb][cb] = __builtin_amdgcn_mfma_f32_16x16x32_bf16(a0[rb][0], b0[cb][0], acc[rb][cb], 0, 0, 0);
        acc[rb][cb] = __builtin_amdgcn_mfma_f32_16x16x32_bf16(a0[rb][1], b0[cb][1], acc[rb][cb], 0, 0, 0);
      }
    __builtin_amdgcn_s_setprio(0);
    __builtin_amdgcn_s_barrier();

    // ---- P2: mq0 x nq1 (4 ds_reads) ----
#pragma unroll
    for (int cb = 0; cb < 2; ++cb) { b1[cb][0] = LDB(2 + cb, q0); b1[cb][1] = LDB(2 + cb, q1); }
    if (u + 1 < NT) STAGE(0, u + 1, 1);          // (u+1) A1
    __builtin_amdgcn_s_barrier();
    asm volatile("s_waitcnt lgkmcnt(0)");
    __builtin_amdgcn_s_setprio(1);
#pragma unroll
    for (int rb = 0; rb < 4; ++rb)
#pragma unroll
      for (int cb = 0; cb < 2; ++cb) {
        acc[rb][2 + cb] = __builtin_amdgcn_mfma_f32_16x16x32_bf16(a0[rb][0], b1[cb][0], acc[rb][2 + cb], 0, 0, 0);
        acc[rb][2 + cb] = __builtin_amdgcn_mfma_f32_16x16x32_bf16(a0[rb][1], b1[cb][1], acc[rb][2 + cb], 0, 0, 0);
      }
    __builtin_amdgcn_s_setprio(0);
    __builtin_amdgcn_s_barrier();

    // ---- P3: mq1 x nq0 (8 ds_reads) ----
#pragma unroll
    for (int rb = 0; rb < 4; ++rb) { a1[rb][0] = LDA(4 + rb, q0); a1[rb][1] = LDA(4 + rb, q1); }
    if (u + 2 < NT) STAGE(1, u + 2, 0);          // (u+2) B0
    __builtin_amdgcn_s_barrier();
    asm volatile("s_waitcnt lgkmcnt(0)");
    __builtin_amdgcn_s_setprio(1);
#pragma unroll
    for (int rb = 0; rb < 4; ++rb)
#pragma unroll
      for (int cb = 0; cb < 2; ++cb) {
        acc[4 + rb][cb] = __builtin_amdgcn_mfma_f32_16x16x32_bf16(a1[rb][0], b0[cb][0], acc[4 + rb][cb], 0, 0, 0);
        acc[4 + rb][cb] = __builtin_amdgcn_mfma_f32_16x16x32_bf16(a1[rb][1], b0[cb][1], acc[4 + rb][cb], 0, 0, 0);
      }
    __builtin_amdgcn_s_setprio(0);
    __builtin_amdgcn_s_barrier();

    // ---- P4: mq1 x nq1 (0 ds_reads) ----
    if (u + 2 < NT) STAGE(1, u + 2, 1);          // (u+2) B1
    __builtin_amdgcn_s_barrier();
    __builtin_amdgcn_s_setprio(1);
#pragma unroll
    for (int rb = 0; rb < 4; ++rb)
#pragma unroll
      for (int cb = 0; cb < 2; ++cb) {
        acc[4 + rb][2 + cb] = __builtin_amdgcn_mfma_f32_16x16x32_bf16(a1[rb][0], b1[cb][0], acc[4 + rb][2 + cb], 0, 0, 0);
        acc[4 + rb][2 + cb] = __builtin_amdgcn_mfma_f32_16x16x32_bf16(a1[rb][1], b1[cb][1], acc[4 + rb][2 + cb], 0, 0, 0);
      }
    __builtin_amdgcn_s_setprio(0);
    // tile-end: counted drain (never 0 until the pipe empties)
    if (u < NT - 2)       { asm volatile("s_waitcnt vmcnt(4)" ::: "memory"); }
    else if (u == NT - 2) { asm volatile("s_waitcnt vmcnt(0)" ::: "memory"); }
    if (u < NT - 1) __builtin_amdgcn_s_barrier();
  }

#undef STAGE
#undef LDA
#undef LDB

  // ---- epilogue: scale/bias fused C write ----
  const float inv127 = 1.0f / 127.0f;
  const int n_base = bn * 256 + wc * 64;
  const int m_base = bm * 256 + wr * 128;
#pragma unroll
  for (int nc = 0; nc < 4; ++nc) {
    const int n = n_base + nc * 16 + fr;
    const float sc = scales[n] * inv127;
    const float bz = bias[n];
#pragma unroll
    for (int rb = 0; rb < 8; ++rb) {
      const int m0 = m_base + rb * 16 + fq * 4;
      float* cp = C + (size_t)m0 * NDIM + n;
#pragma unroll
      for (int r = 0; r < 4; ++r)
        cp[(size_t)r * NDIM] = acc[rb][nc][r] * sc + bz;
    }
  }
}

// ---------------- fallback: fused conversion, reg staging (128^2) ----------------

__global__ __launch_bounds__(256) void gemm_fused(
    const float* __restrict__ X,
    const int* __restrict__ W,
    const float* __restrict__ scales,
    const float* __restrict__ bias,
    float* __restrict__ C) {
  __shared__ unsigned short As[128 * 32];
  __shared__ unsigned short Bs[128 * 32];

  const int tid = threadIdx.x;
  const int lane = tid & 63;
  const int wave = tid >> 6;
  const int wr = wave >> 1, wc = wave & 1;
  const int fr = lane & 15, fq = lane >> 4;

  int id = blockIdx.x;
  int swz = (id & 7) * 128 + (id >> 3);
  const int bm = swz >> 5, bn = swz & 31;

  const int r0 = tid >> 2;
  const int kc = (tid & 3) * 8;
  const size_t aBase = (size_t)(bm * 128 + r0) * KDIM + kc;
  const size_t bBase = (size_t)(bn * 128 + r0) * KDIM + kc;

  f32x4 acc[4][4] = {};

  for (int k0 = 0; k0 < KDIM; k0 += 32) {
    const float* xp = X + aBase + k0;
    const int*   wp = W + bBase + k0;
    fx4 x0 = *(const fx4*)xp;
    fx4 x1 = *(const fx4*)(xp + 4);
    fx4 x2 = *(const fx4*)(xp + (size_t)64 * KDIM);
    fx4 x3 = *(const fx4*)(xp + (size_t)64 * KDIM + 4);
    ix4 w0 = *(const ix4*)wp;
    ix4 w1 = *(const ix4*)(wp + 4);
    ix4 w2 = *(const ix4*)(wp + (size_t)64 * KDIM);
    ix4 w3 = *(const ix4*)(wp + (size_t)64 * KDIM + 4);

    usx8 ca, cb, cc, cd;
#pragma unroll
    for (int j = 0; j < 4; ++j) {
      ca[j] = f32_to_bf16_rne(x0[j]);  ca[j + 4] = f32_to_bf16_rne(x1[j]);
      cb[j] = f32_to_bf16_rne(x2[j]);  cb[j + 4] = f32_to_bf16_rne(x3[j]);
      cc[j] = f32_to_bf16_rne((float)w0[j]); cc[j + 4] = f32_to_bf16_rne((float)w1[j]);
      cd[j] = f32_to_bf16_rne((float)w2[j]); cd[j + 4] = f32_to_bf16_rne((float)w3[j]);
    }

    __syncthreads();
    *reinterpret_cast<usx8*>(As + tid * 8)        = ca;
    *reinterpret_cast<usx8*>(As + 2048 + tid * 8) = cb;
    *reinterpret_cast<usx8*>(Bs + tid * 8)        = cc;
    *reinterpret_cast<usx8*>(Bs + 2048 + tid * 8) = cd;
    __syncthreads();

    bf16x8 af[4], bfr[4];
    const unsigned short* ap = As + (wr * 64 + fr) * 32 + fq * 8;
    const unsigned short* bp = Bs + (wc * 64 + fr) * 32 + fq * 8;
#pragma unroll
    for (int i = 0; i < 4; ++i) {
      af[i]  = *reinterpret_cast<const bf16x8*>(ap + i * 512);
      bfr[i] = *reinterpret_cast<const bf16x8*>(bp + i * 512);
    }
#pragma unroll
    for (int im = 0; im < 4; ++im)
#pragma unroll
      for (int in_ = 0; in_ < 4; ++in_)
        acc[im][in_] = __builtin_amdgcn_mfma_f32_16x16x32_bf16(
            af[im], bfr[in_], acc[im][in_], 0, 0, 0);
  }

  const float inv127 = 1.0f / 127.0f;
#pragma unroll
  for (int in_ = 0; in_ < 4; ++in_) {
    int n = bn * 128 + wc * 64 + in_ * 16 + fr;
    float sc = scales[n] * inv127;
    float bz = bias[n];
#pragma unroll
    for (int im = 0; im < 4; ++im) {
      int m0 = bm * 128 + wr * 64 + im * 16 + fq * 4;
      float* cp = C + (size_t)m0 * NDIM + n;
#pragma unroll
      for (int r = 0; r < 4; ++r)
        cp[(size_t)r * NDIM] = acc[im][in_][r] * sc + bz;
    }
  }
}

// ---------------- host launch ----------------

extern "C" void kernel_launch(void* const* d_in, const int* in_sizes, int n_in,
                              void* d_out, int out_size, void* d_ws, size_t ws_size,
                              hipStream_t stream) {
  const float* x      = (const float*)d_in[0];
  const int*   w8     = (const int*)d_in[1];
  const float* scales = (const float*)d_in[2];
  // d_in[3] = weight_fp : unused by the reference
  const float* bias   = (const float*)d_in[4];
  float* out = (float*)d_out;

  const size_t xb_elems = (size_t)MDIM * KDIM;
  const size_t wb_elems = (size_t)NDIM * KDIM;
  const size_t need = (xb_elems + wb_elems) * sizeof(unsigned short);

  if (ws_size >= need) {
    unsigned short* xb = (unsigned short*)d_ws;
    unsigned short* wb = xb + xb_elems;
    int n8 = (int)(xb_elems / 8);
    cvt_x_kernel<<<2048, 256, 0, stream>>>(x, xb, n8);
    cvt_w_kernel<<<2048, 256, 0, stream>>>(w8, wb, n8);
    gemm_8ph<<<256, 512, 0, stream>>>(xb, wb, scales, bias, out);
  } else {
    gemm_fused<<<1024, 256, 0, stream>>>(x, w8, scales, bias, out);
  }
}

// Round 3
// 144.922 us; speedup vs baseline: 1.4927x; 1.1224x over previous
//
#include <hip/hip_runtime.h>
#include <hip/hip_bf16.h>
#include <stdint.h>

// Problem constants (B=2, S=2048, IN=4096, OUT=4096)
#define MDIM 4096   // B*S
#define NDIM 4096   // OUT
#define KDIM 4096   // IN
#define NT   (KDIM / 64)   // 64 K-tiles of BK=64

typedef __attribute__((ext_vector_type(4))) float  f32x4;
typedef __attribute__((ext_vector_type(8))) short  bf16x8;
typedef __attribute__((ext_vector_type(4))) float  fx4;
typedef __attribute__((ext_vector_type(4))) int    ix4;
typedef __attribute__((ext_vector_type(8))) unsigned short usx8;

__device__ static inline unsigned short f32_to_bf16_rne(float f) {
  union { float f; unsigned int u; } v; v.f = f;
  unsigned int u = v.u;
  u += 0x7fffu + ((u >> 16) & 1u);
  return (unsigned short)(u >> 16);
}

__device__ static inline void gload_lds16(const unsigned short* g, unsigned short* l) {
  __builtin_amdgcn_global_load_lds((const __attribute__((address_space(1))) void*)g,
                                   (__attribute__((address_space(3))) void*)l,
                                   16, 0, 0);
}

// ---------------- conversion kernels ----------------

__global__ void cvt_x_kernel(const float* __restrict__ in,
                             unsigned short* __restrict__ out, int n8) {
  int idx = blockIdx.x * blockDim.x + threadIdx.x;
  int stride = gridDim.x * blockDim.x;
  for (int i = idx; i < n8; i += stride) {
    const fx4* p = reinterpret_cast<const fx4*>(in) + (size_t)i * 2;
    fx4 a = p[0], b = p[1];
    usx8 r;
    r[0] = f32_to_bf16_rne(a[0]); r[1] = f32_to_bf16_rne(a[1]);
    r[2] = f32_to_bf16_rne(a[2]); r[3] = f32_to_bf16_rne(a[3]);
    r[4] = f32_to_bf16_rne(b[0]); r[5] = f32_to_bf16_rne(b[1]);
    r[6] = f32_to_bf16_rne(b[2]); r[7] = f32_to_bf16_rne(b[3]);
    reinterpret_cast<usx8*>(out)[i] = r;
  }
}

__global__ void cvt_w_kernel(const int* __restrict__ in,
                             unsigned short* __restrict__ out, int n8) {
  int idx = blockIdx.x * blockDim.x + threadIdx.x;
  int stride = gridDim.x * blockDim.x;
  for (int i = idx; i < n8; i += stride) {
    const ix4* p = reinterpret_cast<const ix4*>(in) + (size_t)i * 2;
    ix4 a = p[0], b = p[1];
    usx8 r;
    r[0] = f32_to_bf16_rne((float)a[0]); r[1] = f32_to_bf16_rne((float)a[1]);
    r[2] = f32_to_bf16_rne((float)a[2]); r[3] = f32_to_bf16_rne((float)a[3]);
    r[4] = f32_to_bf16_rne((float)b[0]); r[5] = f32_to_bf16_rne((float)b[1]);
    r[6] = f32_to_bf16_rne((float)b[2]); r[7] = f32_to_bf16_rne((float)b[3]);
    reinterpret_cast<usx8*>(out)[i] = r;
  }
}

// ---------------- 256x256 pipelined 4-phase GEMM ----------------
// 512 threads = 8 waves (2M x 4N). Per-wave output 128x64. BK=64.
// LDS = 2 dbuf x (256x64 A + 256x64 B) bf16 = 128 KiB.
//
// Pipelined read schedule (reads issued ONE PHASE AHEAD, drained by
// compiler-inserted counted lgkmcnt at the MFMA use point, so the LDS
// read burst overlaps the current phase's MFMA burst):
//   tile-end(u-1): read a0,b0 (12)   [for P1]
//   P1: read b1 (4)  [for P2]; MFMA(a0,b0);  barrier
//   P2: read a1 (8)  [for P3]; MFMA(a0,b1);  barrier
//   P3: stage (u+2)B0,B1;       MFMA(a1,b0);  barrier
//   P4: stage (u+2)A0,A1;       MFMA(a1,b1);  vmcnt; barrier; read-ahead
// Region-lifetime safety:
//   - B regions last READ-ISSUED at P1 (b1), drained before P2 MFMA (reg
//     dependency), all waves past P2 barrier -> stage B at P3 safe.
//   - A regions last read-issued at P2 (a1), drained before P3 MFMA,
//     all waves past P3 barrier -> stage A at P4 safe.
//   - read-ahead of tile u+1 issued only after vmcnt(8) (drains (u+1)'s
//     8 staging loads) + barrier (all waves' vmcnt passed) -> LDS data
//     from OTHER waves' global_load_lds is visible.
// vmcnt ledger (2 gloads per STAGE, 8 per tile, all issued P3/P4):
//   entering tile u: 8 outstanding = (u+1)'s halves. +8 during tile.
//   tile-end vmcnt(8) -> (u+1) landed, (u+2)'s 8 stay in flight.
//   u==NT-2: stages skipped -> vmcnt(0) drains (NT-1)'s. u==NT-1: none.
// LDS swizzle: slot q of 8x16B stored at q^(row&7); gload_lds writes
// linearly with pre-swizzled per-lane GLOBAL source; ds_read applies the
// same XOR (verified: SQ_LDS_BANK_CONFLICT == 0).

__global__ __launch_bounds__(512, 2) void gemm_8ph(
    const unsigned short* __restrict__ A,    // [M][K] bf16 bits
    const unsigned short* __restrict__ Bw,   // [N][K] bf16 bits
    const float* __restrict__ scales,
    const float* __restrict__ bias,
    float* __restrict__ C) {
  __shared__ unsigned short Ash[32768];   // 64 KiB: [2][256][64]
  __shared__ unsigned short Bsh[32768];   // 64 KiB

  const int tid = threadIdx.x;
  const int w   = tid >> 6;          // wave 0..7
  const int l   = tid & 63;
  const int wr  = w >> 2;            // 0..1 : M half
  const int wc  = w & 3;             // 0..3 : N quarter
  const int fr  = l & 15;            // fragment row
  const int fq  = l >> 4;            // fragment k-quarter / C row group

  // XCD-aware swizzle: 256 blocks, 256 % 8 == 0 -> simple bijective form
  const int id  = blockIdx.x;
  const int swz = (id & 7) * 32 + (id >> 3);
  const int bm  = swz >> 4, bn = swz & 15;

  const unsigned short* aorg = A  + (size_t)(bm * 256) * KDIM;
  const unsigned short* borg = Bw + (size_t)(bn * 256) * KDIM;

  // staging per-thread global offset (pre-swizzled source)
  const int lr = l >> 3;                 // row-in-octet 0..7
  const int ks = (l & 7) ^ lr;           // swizzled k-slot
  const size_t g_off = (size_t)(w * 16 + lr) * KDIM + (size_t)ks * 8;
  const int    s_off = w * 1024;         // lds elems (wave-uniform)

#define STAGE(isB, t, h) do {                                                   \
    const unsigned short* _g = ((isB) ? borg : aorg)                            \
        + (size_t)(h) * 128 * KDIM + (size_t)(t) * 64 + g_off;                  \
    unsigned short* _l = ((isB) ? Bsh : Ash)                                    \
        + (((t) & 1) * 16384 + (h) * 8192 + s_off);                             \
    gload_lds16(_g, _l);                                                        \
    gload_lds16(_g + 8 * KDIM, _l + 512);                                       \
  } while (0)

  // ds_read offsets (swizzled)
  const int arow = (wr * 128 + fr) * 64;
  const int brow = (wc * 64  + fr) * 64;
  const int q0 = ((fq)     ^ (fr & 7)) * 8;   // k-half 0 slot
  const int q1 = ((4 + fq) ^ (fr & 7)) * 8;   // k-half 1 slot

#define LDA(off, rb, qq) (*(const bf16x8*)(Ash + (off) + arow + (rb) * 1024 + (qq)))
#define LDB(off, nc, qq) (*(const bf16x8*)(Bsh + (off) + brow + (nc) * 1024 + (qq)))

  f32x4 acc[8][4] = {};
  bf16x8 a0[4][2], a1[4][2], b0[2][2], b1[2][2];

  // ---- prologue: stage t0 + t1 fully (16 loads), land t0, pre-read P1 ----
  STAGE(0, 0, 0); STAGE(0, 0, 1); STAGE(1, 0, 0); STAGE(1, 0, 1);
  STAGE(0, 1, 0); STAGE(0, 1, 1); STAGE(1, 1, 0); STAGE(1, 1, 1);
  asm volatile("s_waitcnt vmcnt(8)" ::: "memory");   // t0 landed, t1 in flight
  __builtin_amdgcn_s_barrier();
#pragma unroll
  for (int rb = 0; rb < 4; ++rb) { a0[rb][0] = LDA(0, rb, q0); a0[rb][1] = LDA(0, rb, q1); }
#pragma unroll
  for (int cb = 0; cb < 2; ++cb) { b0[cb][0] = LDB(0, cb, q0); b0[cb][1] = LDB(0, cb, q1); }

#pragma unroll 2
  for (int u = 0; u < NT; ++u) {
    const int cur = (u & 1) * 16384;
    const int nxt = cur ^ 16384;

    // ---- P1: MFMA(a0,b0) ; pre-read b1 for P2 ----
#pragma unroll
    for (int cb = 0; cb < 2; ++cb) { b1[cb][0] = LDB(cur, 2 + cb, q0); b1[cb][1] = LDB(cur, 2 + cb, q1); }
    __builtin_amdgcn_s_setprio(1);
#pragma unroll
    for (int rb = 0; rb < 4; ++rb)
#pragma unroll
      for (int cb = 0; cb < 2; ++cb) {
        acc[rb][cb] = __builtin_amdgcn_mfma_f32_16x16x32_bf16(a0[rb][0], b0[cb][0], acc[rb][cb], 0, 0, 0);
        acc[rb][cb] = __builtin_amdgcn_mfma_f32_16x16x32_bf16(a0[rb][1], b0[cb][1], acc[rb][cb], 0, 0, 0);
      }
    __builtin_amdgcn_s_setprio(0);
    __builtin_amdgcn_s_barrier();

    // ---- P2: MFMA(a0,b1) ; pre-read a1 for P3 ----
#pragma unroll
    for (int rb = 0; rb < 4; ++rb) { a1[rb][0] = LDA(cur, 4 + rb, q0); a1[rb][1] = LDA(cur, 4 + rb, q1); }
    __builtin_amdgcn_s_setprio(1);
#pragma unroll
    for (int rb = 0; rb < 4; ++rb)
#pragma unroll
      for (int cb = 0; cb < 2; ++cb) {
        acc[rb][2 + cb] = __builtin_amdgcn_mfma_f32_16x16x32_bf16(a0[rb][0], b1[cb][0], acc[rb][2 + cb], 0, 0, 0);
        acc[rb][2 + cb] = __builtin_amdgcn_mfma_f32_16x16x32_bf16(a0[rb][1], b1[cb][1], acc[rb][2 + cb], 0, 0, 0);
      }
    __builtin_amdgcn_s_setprio(0);
    __builtin_amdgcn_s_barrier();

    // ---- P3: stage (u+2) B halves ; MFMA(a1,b0) ----
    if (u + 2 < NT) { STAGE(1, u + 2, 0); STAGE(1, u + 2, 1); }
    __builtin_amdgcn_s_setprio(1);
#pragma unroll
    for (int rb = 0; rb < 4; ++rb)
#pragma unroll
      for (int cb = 0; cb < 2; ++cb) {
        acc[4 + rb][cb] = __builtin_amdgcn_mfma_f32_16x16x32_bf16(a1[rb][0], b0[cb][0], acc[4 + rb][cb], 0, 0, 0);
        acc[4 + rb][cb] = __builtin_amdgcn_mfma_f32_16x16x32_bf16(a1[rb][1], b0[cb][1], acc[4 + rb][cb], 0, 0, 0);
      }
    __builtin_amdgcn_s_setprio(0);
    __builtin_amdgcn_s_barrier();

    // ---- P4: stage (u+2) A halves ; MFMA(a1,b1) ; tile-end sync ----
    if (u + 2 < NT) { STAGE(0, u + 2, 0); STAGE(0, u + 2, 1); }
    __builtin_amdgcn_s_setprio(1);
#pragma unroll
    for (int rb = 0; rb < 4; ++rb)
#pragma unroll
      for (int cb = 0; cb < 2; ++cb) {
        acc[4 + rb][2 + cb] = __builtin_amdgcn_mfma_f32_16x16x32_bf16(a1[rb][0], b1[cb][0], acc[4 + rb][2 + cb], 0, 0, 0);
        acc[4 + rb][2 + cb] = __builtin_amdgcn_mfma_f32_16x16x32_bf16(a1[rb][1], b1[cb][1], acc[4 + rb][2 + cb], 0, 0, 0);
      }
    __builtin_amdgcn_s_setprio(0);
    if (u < NT - 2)       { asm volatile("s_waitcnt vmcnt(8)" ::: "memory"); }
    else if (u == NT - 2) { asm volatile("s_waitcnt vmcnt(0)" ::: "memory"); }
    if (u < NT - 1) {
      __builtin_amdgcn_s_barrier();
      // read-ahead: next tile's P1 fragments (a0,b0) from buf[nxt]
#pragma unroll
      for (int rb = 0; rb < 4; ++rb) { a0[rb][0] = LDA(nxt, rb, q0); a0[rb][1] = LDA(nxt, rb, q1); }
#pragma unroll
      for (int cb = 0; cb < 2; ++cb) { b0[cb][0] = LDB(nxt, cb, q0); b0[cb][1] = LDB(nxt, cb, q1); }
    }
  }

#undef STAGE
#undef LDA
#undef LDB

  // ---- epilogue: scale/bias fused C write ----
  const float inv127 = 1.0f / 127.0f;
  const int n_base = bn * 256 + wc * 64;
  const int m_base = bm * 256 + wr * 128;
#pragma unroll
  for (int nc = 0; nc < 4; ++nc) {
    const int n = n_base + nc * 16 + fr;
    const float sc = scales[n] * inv127;
    const float bz = bias[n];
#pragma unroll
    for (int rb = 0; rb < 8; ++rb) {
      const int m0 = m_base + rb * 16 + fq * 4;
      float* cp = C + (size_t)m0 * NDIM + n;
#pragma unroll
      for (int r = 0; r < 4; ++r)
        cp[(size_t)r * NDIM] = acc[rb][nc][r] * sc + bz;
    }
  }
}

// ---------------- fallback: fused conversion, reg staging (128^2) ----------------

__global__ __launch_bounds__(256) void gemm_fused(
    const float* __restrict__ X,
    const int* __restrict__ W,
    const float* __restrict__ scales,
    const float* __restrict__ bias,
    float* __restrict__ C) {
  __shared__ unsigned short As[128 * 32];
  __shared__ unsigned short Bs[128 * 32];

  const int tid = threadIdx.x;
  const int lane = tid & 63;
  const int wave = tid >> 6;
  const int wr = wave >> 1, wc = wave & 1;
  const int fr = lane & 15, fq = lane >> 4;

  int id = blockIdx.x;
  int swz = (id & 7) * 128 + (id >> 3);
  const int bm = swz >> 5, bn = swz & 31;

  const int r0 = tid >> 2;
  const int kc = (tid & 3) * 8;
  const size_t aBase = (size_t)(bm * 128 + r0) * KDIM + kc;
  const size_t bBase = (size_t)(bn * 128 + r0) * KDIM + kc;

  f32x4 acc[4][4] = {};

  for (int k0 = 0; k0 < KDIM; k0 += 32) {
    const float* xp = X + aBase + k0;
    const int*   wp = W + bBase + k0;
    fx4 x0 = *(const fx4*)xp;
    fx4 x1 = *(const fx4*)(xp + 4);
    fx4 x2 = *(const fx4*)(xp + (size_t)64 * KDIM);
    fx4 x3 = *(const fx4*)(xp + (size_t)64 * KDIM + 4);
    ix4 w0 = *(const ix4*)wp;
    ix4 w1 = *(const ix4*)(wp + 4);
    ix4 w2 = *(const ix4*)(wp + (size_t)64 * KDIM);
    ix4 w3 = *(const ix4*)(wp + (size_t)64 * KDIM + 4);

    usx8 ca, cb, cc, cd;
#pragma unroll
    for (int j = 0; j < 4; ++j) {
      ca[j] = f32_to_bf16_rne(x0[j]);  ca[j + 4] = f32_to_bf16_rne(x1[j]);
      cb[j] = f32_to_bf16_rne(x2[j]);  cb[j + 4] = f32_to_bf16_rne(x3[j]);
      cc[j] = f32_to_bf16_rne((float)w0[j]); cc[j + 4] = f32_to_bf16_rne((float)w1[j]);
      cd[j] = f32_to_bf16_rne((float)w2[j]); cd[j + 4] = f32_to_bf16_rne((float)w3[j]);
    }

    __syncthreads();
    *reinterpret_cast<usx8*>(As + tid * 8)        = ca;
    *reinterpret_cast<usx8*>(As + 2048 + tid * 8) = cb;
    *reinterpret_cast<usx8*>(Bs + tid * 8)        = cc;
    *reinterpret_cast<usx8*>(Bs + 2048 + tid * 8) = cd;
    __syncthreads();

    bf16x8 af[4], bfr[4];
    const unsigned short* ap = As + (wr * 64 + fr) * 32 + fq * 8;
    const unsigned short* bp = Bs + (wc * 64 + fr) * 32 + fq * 8;
#pragma unroll
    for (int i = 0; i < 4; ++i) {
      af[i]  = *reinterpret_cast<const bf16x8*>(ap + i * 512);
      bfr[i] = *reinterpret_cast<const bf16x8*>(bp + i * 512);
    }
#pragma unroll
    for (int im = 0; im < 4; ++im)
#pragma unroll
      for (int in_ = 0; in_ < 4; ++in_)
        acc[im][in_] = __builtin_amdgcn_mfma_f32_16x16x32_bf16(
            af[im], bfr[in_], acc[im][in_], 0, 0, 0);
  }

  const float inv127 = 1.0f / 127.0f;
#pragma unroll
  for (int in_ = 0; in_ < 4; ++in_) {
    int n = bn * 128 + wc * 64 + in_ * 16 + fr;
    float sc = scales[n] * inv127;
    float bz = bias[n];
#pragma unroll
    for (int im = 0; im < 4; ++im) {
      int m0 = bm * 128 + wr * 64 + im * 16 + fq * 4;
      float* cp = C + (size_t)m0 * NDIM + n;
#pragma unroll
      for (int r = 0; r < 4; ++r)
        cp[(size_t)r * NDIM] = acc[im][in_][r] * sc + bz;
    }
  }
}

// ---------------- host launch ----------------

extern "C" void kernel_launch(void* const* d_in, const int* in_sizes, int n_in,
                              void* d_out, int out_size, void* d_ws, size_t ws_size,
                              hipStream_t stream) {
  const float* x      = (const float*)d_in[0];
  const int*   w8     = (const int*)d_in[1];
  const float* scales = (const float*)d_in[2];
  // d_in[3] = weight_fp : unused by the reference
  const float* bias   = (const float*)d_in[4];
  float* out = (float*)d_out;

  const size_t xb_elems = (size_t)MDIM * KDIM;
  const size_t wb_elems = (size_t)NDIM * KDIM;
  const size_t need = (xb_elems + wb_elems) * sizeof(unsigned short);

  if (ws_size >= need) {
    unsigned short* xb = (unsigned short*)d_ws;
    unsigned short* wb = xb + xb_elems;
    int n8 = (int)(xb_elems / 8);
    cvt_x_kernel<<<2048, 256, 0, stream>>>(x, xb, n8);
    cvt_w_kernel<<<2048, 256, 0, stream>>>(w8, wb, n8);
    gemm_8ph<<<256, 512, 0, stream>>>(xb, wb, scales, bias, out);
  } else {
    gemm_fused<<<1024, 256, 0, stream>>>(x, w8, scales, bias, out);
  }
}

// Round 4
// 141.851 us; speedup vs baseline: 1.5250x; 1.0217x over previous
//
#include <hip/hip_runtime.h>
#include <hip/hip_bf16.h>
#include <stdint.h>

// Problem constants (B=2, S=2048, IN=4096, OUT=4096)
#define MDIM 4096   // B*S
#define NDIM 4096   // OUT
#define KDIM 4096   // IN
#define NT   (KDIM / 64)   // 64 K-tiles of BK=64

typedef __attribute__((ext_vector_type(4))) float  f32x4;
typedef __attribute__((ext_vector_type(8))) short  bf16x8;
typedef __attribute__((ext_vector_type(4))) float  fx4;
typedef __attribute__((ext_vector_type(4))) int    ix4;
typedef __attribute__((ext_vector_type(8))) unsigned short usx8;

__device__ static inline unsigned short f32_to_bf16_rne(float f) {
  union { float f; unsigned int u; } v; v.f = f;
  unsigned int u = v.u;
  u += 0x7fffu + ((u >> 16) & 1u);
  return (unsigned short)(u >> 16);
}

__device__ static inline void gload_lds16(const unsigned short* g, unsigned short* l) {
  __builtin_amdgcn_global_load_lds((const __attribute__((address_space(1))) void*)g,
                                   (__attribute__((address_space(3))) void*)l,
                                   16, 0, 0);
}

// ---------------- merged conversion kernel ----------------
// x (fp32->bf16) and w (int32->bf16) are independent streams; one kernel
// runs them concurrently (separate kernels would serialize on the stream).

__global__ void cvt_both_kernel(const float* __restrict__ xin,
                                const int* __restrict__ win,
                                unsigned short* __restrict__ xout,
                                unsigned short* __restrict__ wout, int n8each) {
  int idx = blockIdx.x * blockDim.x + threadIdx.x;
  int stride = gridDim.x * blockDim.x;
  for (int i = idx; i < 2 * n8each; i += stride) {
    usx8 r;
    if (i < n8each) {
      const fx4* p = reinterpret_cast<const fx4*>(xin) + (size_t)i * 2;
      fx4 a = p[0], b = p[1];
      r[0] = f32_to_bf16_rne(a[0]); r[1] = f32_to_bf16_rne(a[1]);
      r[2] = f32_to_bf16_rne(a[2]); r[3] = f32_to_bf16_rne(a[3]);
      r[4] = f32_to_bf16_rne(b[0]); r[5] = f32_to_bf16_rne(b[1]);
      r[6] = f32_to_bf16_rne(b[2]); r[7] = f32_to_bf16_rne(b[3]);
      reinterpret_cast<usx8*>(xout)[i] = r;
    } else {
      int j = i - n8each;
      const ix4* p = reinterpret_cast<const ix4*>(win) + (size_t)j * 2;
      ix4 a = p[0], b = p[1];
      r[0] = f32_to_bf16_rne((float)a[0]); r[1] = f32_to_bf16_rne((float)a[1]);
      r[2] = f32_to_bf16_rne((float)a[2]); r[3] = f32_to_bf16_rne((float)a[3]);
      r[4] = f32_to_bf16_rne((float)b[0]); r[5] = f32_to_bf16_rne((float)b[1]);
      r[6] = f32_to_bf16_rne((float)b[2]); r[7] = f32_to_bf16_rne((float)b[3]);
      reinterpret_cast<usx8*>(wout)[j] = r;
    }
  }
}

// ---------------- 256x256 pipelined 2-barrier GEMM ----------------
// 512 threads = 8 waves (2M x 4N). Per-wave output 128x64. BK=64.
// LDS = 2 dbuf x (256x64 A + 256x64 B) bf16 = 128 KiB.
//
// Tile schedule (2 barriers/tile; reads pipelined one burst ahead):
//   [tile bottom of u-1: read a0,b0 (12) from buf cur]
//   Phase A: read b1,a1 (12); 32 MFMA (a0 x {b0,b1});
//            lgkmcnt(0)  [free: reads are >=1 MFMA-burst old]
//            barrier     -> ALL waves' ds_reads of cur are DRAINED
//   Phase B: stage tile (u+2) all 4 halves into cur (8 gloads);
//            32 MFMA (a1 x {b0,b1});
//            vmcnt(8)    -> (u+1)'s 8 staging loads landed, (u+2)'s in flight
//            barrier; read-ahead a0,b0 of tile u+1 from nxt (12)
// Region-lifetime safety:
//   - stage->cur at Phase B: every ds_read of cur (a0,b0 at boundary; b1,a1
//     at Phase A) drained by the explicit lgkmcnt(0) before the Phase-A
//     barrier; all waves past that barrier before any stage issues.
//   - cur is not ds_read again until tile u+2, which is gated by tile-(u+1)
//     bottom vmcnt(8)+barrier (drains (u+2)'s gloads, makes them visible).
//   - read-ahead touches nxt only; stages touch cur only.
// vmcnt ledger: entering tile u: 8 outstanding ((u+1)'s). +8 in Phase B.
//   vmcnt(8) keeps (u+2)'s in flight. u==NT-2: no stage -> vmcnt(0) drains
//   (NT-1)'s. u==NT-1: no stage, no wait.
// Compiler-visible ds_reads/gloads: hipcc inserts exact lgkm/vm waits before
// register uses; the asm waits only gate cross-wave LDS reuse (m201 pattern).

__global__ __launch_bounds__(512, 2) void gemm_2bar(
    const unsigned short* __restrict__ A,    // [M][K] bf16 bits
    const unsigned short* __restrict__ Bw,   // [N][K] bf16 bits
    const float* __restrict__ scales,
    const float* __restrict__ bias,
    float* __restrict__ C) {
  __shared__ unsigned short Ash[32768];   // 64 KiB: [2][256][64]
  __shared__ unsigned short Bsh[32768];   // 64 KiB

  const int tid = threadIdx.x;
  const int w   = tid >> 6;          // wave 0..7
  const int l   = tid & 63;
  const int wr  = w >> 2;            // 0..1 : M half
  const int wc  = w & 3;             // 0..3 : N quarter
  const int fr  = l & 15;            // fragment row
  const int fq  = l >> 4;            // fragment k-quarter / C row group

  // XCD-aware swizzle: 256 blocks, 256 % 8 == 0 -> simple bijective form
  const int id  = blockIdx.x;
  const int swz = (id & 7) * 32 + (id >> 3);
  const int bm  = swz >> 4, bn = swz & 15;

  const unsigned short* aorg = A  + (size_t)(bm * 256) * KDIM;
  const unsigned short* borg = Bw + (size_t)(bn * 256) * KDIM;

  // staging per-thread global offset (pre-swizzled source)
  const int lr = l >> 3;                 // row-in-octet 0..7
  const int ks = (l & 7) ^ lr;           // swizzled k-slot
  const size_t g_off = (size_t)(w * 16 + lr) * KDIM + (size_t)ks * 8;
  const int    s_off = w * 1024;         // lds elems (wave-uniform)

#define STAGE(isB, t, h) do {                                                   \
    const unsigned short* _g = ((isB) ? borg : aorg)                            \
        + (size_t)(h) * 128 * KDIM + (size_t)(t) * 64 + g_off;                  \
    unsigned short* _l = ((isB) ? Bsh : Ash)                                    \
        + (((t) & 1) * 16384 + (h) * 8192 + s_off);                             \
    gload_lds16(_g, _l);                                                        \
    gload_lds16(_g + 8 * KDIM, _l + 512);                                       \
  } while (0)

  // ds_read offsets (swizzled: slot q of 8x16B stored at q^(row&7);
  // verified SQ_LDS_BANK_CONFLICT == 0)
  const int arow = (wr * 128 + fr) * 64;
  const int brow = (wc * 64  + fr) * 64;
  const int q0 = ((fq)     ^ (fr & 7)) * 8;   // k-half 0 slot
  const int q1 = ((4 + fq) ^ (fr & 7)) * 8;   // k-half 1 slot

#define LDA(off, rb, qq) (*(const bf16x8*)(Ash + (off) + arow + (rb) * 1024 + (qq)))
#define LDB(off, nc, qq) (*(const bf16x8*)(Bsh + (off) + brow + (nc) * 1024 + (qq)))

  f32x4 acc[8][4] = {};
  bf16x8 a0[4][2], a1[4][2], b0[2][2], b1[2][2];

  // ---- prologue: stage t0 + t1 fully (16 loads), land t0, pre-read ----
  STAGE(0, 0, 0); STAGE(0, 0, 1); STAGE(1, 0, 0); STAGE(1, 0, 1);
  STAGE(0, 1, 0); STAGE(0, 1, 1); STAGE(1, 1, 0); STAGE(1, 1, 1);
  asm volatile("s_waitcnt vmcnt(8)" ::: "memory");   // t0 landed, t1 in flight
  __builtin_amdgcn_s_barrier();
#pragma unroll
  for (int rb = 0; rb < 4; ++rb) { a0[rb][0] = LDA(0, rb, q0); a0[rb][1] = LDA(0, rb, q1); }
#pragma unroll
  for (int cb = 0; cb < 2; ++cb) { b0[cb][0] = LDB(0, cb, q0); b0[cb][1] = LDB(0, cb, q1); }

#pragma unroll 2
  for (int u = 0; u < NT; ++u) {
    const int cur = (u & 1) * 16384;
    const int nxt = cur ^ 16384;

    // ---- Phase A: pre-read b1,a1 ; MFMA(a0 x {b0,b1}) ----
#pragma unroll
    for (int cb = 0; cb < 2; ++cb) { b1[cb][0] = LDB(cur, 2 + cb, q0); b1[cb][1] = LDB(cur, 2 + cb, q1); }
#pragma unroll
    for (int rb = 0; rb < 4; ++rb) { a1[rb][0] = LDA(cur, 4 + rb, q0); a1[rb][1] = LDA(cur, 4 + rb, q1); }
    __builtin_amdgcn_s_setprio(1);
#pragma unroll
    for (int rb = 0; rb < 4; ++rb)
#pragma unroll
      for (int cb = 0; cb < 2; ++cb) {
        acc[rb][cb] = __builtin_amdgcn_mfma_f32_16x16x32_bf16(a0[rb][0], b0[cb][0], acc[rb][cb], 0, 0, 0);
        acc[rb][cb] = __builtin_amdgcn_mfma_f32_16x16x32_bf16(a0[rb][1], b0[cb][1], acc[rb][cb], 0, 0, 0);
      }
#pragma unroll
    for (int rb = 0; rb < 4; ++rb)
#pragma unroll
      for (int cb = 0; cb < 2; ++cb) {
        acc[rb][2 + cb] = __builtin_amdgcn_mfma_f32_16x16x32_bf16(a0[rb][0], b1[cb][0], acc[rb][2 + cb], 0, 0, 0);
        acc[rb][2 + cb] = __builtin_amdgcn_mfma_f32_16x16x32_bf16(a0[rb][1], b1[cb][1], acc[rb][2 + cb], 0, 0, 0);
      }
    __builtin_amdgcn_s_setprio(0);
    asm volatile("s_waitcnt lgkmcnt(0)" ::: "memory");   // all cur reads drained (cheap)
    __builtin_amdgcn_s_barrier();

    // ---- Phase B: stage (u+2) into cur ; MFMA(a1 x {b0,b1}) ----
    if (u + 2 < NT) { STAGE(1, u + 2, 0); STAGE(1, u + 2, 1); STAGE(0, u + 2, 0); STAGE(0, u + 2, 1); }
    __builtin_amdgcn_s_setprio(1);
#pragma unroll
    for (int rb = 0; rb < 4; ++rb)
#pragma unroll
      for (int cb = 0; cb < 2; ++cb) {
        acc[4 + rb][cb] = __builtin_amdgcn_mfma_f32_16x16x32_bf16(a1[rb][0], b0[cb][0], acc[4 + rb][cb], 0, 0, 0);
        acc[4 + rb][cb] = __builtin_amdgcn_mfma_f32_16x16x32_bf16(a1[rb][1], b0[cb][1], acc[4 + rb][cb], 0, 0, 0);
      }
#pragma unroll
    for (int rb = 0; rb < 4; ++rb)
#pragma unroll
      for (int cb = 0; cb < 2; ++cb) {
        acc[4 + rb][2 + cb] = __builtin_amdgcn_mfma_f32_16x16x32_bf16(a1[rb][0], b1[cb][0], acc[4 + rb][2 + cb], 0, 0, 0);
        acc[4 + rb][2 + cb] = __builtin_amdgcn_mfma_f32_16x16x32_bf16(a1[rb][1], b1[cb][1], acc[4 + rb][2 + cb], 0, 0, 0);
      }
    __builtin_amdgcn_s_setprio(0);
    if (u < NT - 2)       { asm volatile("s_waitcnt vmcnt(8)" ::: "memory"); }
    else if (u == NT - 2) { asm volatile("s_waitcnt vmcnt(0)" ::: "memory"); }
    if (u < NT - 1) {
      __builtin_amdgcn_s_barrier();
      // read-ahead: next tile's first-burst fragments from buf[nxt]
#pragma unroll
      for (int rb = 0; rb < 4; ++rb) { a0[rb][0] = LDA(nxt, rb, q0); a0[rb][1] = LDA(nxt, rb, q1); }
#pragma unroll
      for (int cb = 0; cb < 2; ++cb) { b0[cb][0] = LDB(nxt, cb, q0); b0[cb][1] = LDB(nxt, cb, q1); }
    }
  }

#undef STAGE
#undef LDA
#undef LDB

  // ---- epilogue: scale/bias fused C write ----
  const float inv127 = 1.0f / 127.0f;
  const int n_base = bn * 256 + wc * 64;
  const int m_base = bm * 256 + wr * 128;
#pragma unroll
  for (int nc = 0; nc < 4; ++nc) {
    const int n = n_base + nc * 16 + fr;
    const float sc = scales[n] * inv127;
    const float bz = bias[n];
#pragma unroll
    for (int rb = 0; rb < 8; ++rb) {
      const int m0 = m_base + rb * 16 + fq * 4;
      float* cp = C + (size_t)m0 * NDIM + n;
#pragma unroll
      for (int r = 0; r < 4; ++r)
        cp[(size_t)r * NDIM] = acc[rb][nc][r] * sc + bz;
    }
  }
}

// ---------------- fallback: fused conversion, reg staging (128^2) ----------------

__global__ __launch_bounds__(256) void gemm_fused(
    const float* __restrict__ X,
    const int* __restrict__ W,
    const float* __restrict__ scales,
    const float* __restrict__ bias,
    float* __restrict__ C) {
  __shared__ unsigned short As[128 * 32];
  __shared__ unsigned short Bs[128 * 32];

  const int tid = threadIdx.x;
  const int lane = tid & 63;
  const int wave = tid >> 6;
  const int wr = wave >> 1, wc = wave & 1;
  const int fr = lane & 15, fq = lane >> 4;

  int id = blockIdx.x;
  int swz = (id & 7) * 128 + (id >> 3);
  const int bm = swz >> 5, bn = swz & 31;

  const int r0 = tid >> 2;
  const int kc = (tid & 3) * 8;
  const size_t aBase = (size_t)(bm * 128 + r0) * KDIM + kc;
  const size_t bBase = (size_t)(bn * 128 + r0) * KDIM + kc;

  f32x4 acc[4][4] = {};

  for (int k0 = 0; k0 < KDIM; k0 += 32) {
    const float* xp = X + aBase + k0;
    const int*   wp = W + bBase + k0;
    fx4 x0 = *(const fx4*)xp;
    fx4 x1 = *(const fx4*)(xp + 4);
    fx4 x2 = *(const fx4*)(xp + (size_t)64 * KDIM);
    fx4 x3 = *(const fx4*)(xp + (size_t)64 * KDIM + 4);
    ix4 w0 = *(const ix4*)wp;
    ix4 w1 = *(const ix4*)(wp + 4);
    ix4 w2 = *(const ix4*)(wp + (size_t)64 * KDIM);
    ix4 w3 = *(const ix4*)(wp + (size_t)64 * KDIM + 4);

    usx8 ca, cb, cc, cd;
#pragma unroll
    for (int j = 0; j < 4; ++j) {
      ca[j] = f32_to_bf16_rne(x0[j]);  ca[j + 4] = f32_to_bf16_rne(x1[j]);
      cb[j] = f32_to_bf16_rne(x2[j]);  cb[j + 4] = f32_to_bf16_rne(x3[j]);
      cc[j] = f32_to_bf16_rne((float)w0[j]); cc[j + 4] = f32_to_bf16_rne((float)w1[j]);
      cd[j] = f32_to_bf16_rne((float)w2[j]); cd[j + 4] = f32_to_bf16_rne((float)w3[j]);
    }

    __syncthreads();
    *reinterpret_cast<usx8*>(As + tid * 8)        = ca;
    *reinterpret_cast<usx8*>(As + 2048 + tid * 8) = cb;
    *reinterpret_cast<usx8*>(Bs + tid * 8)        = cc;
    *reinterpret_cast<usx8*>(Bs + 2048 + tid * 8) = cd;
    __syncthreads();

    bf16x8 af[4], bfr[4];
    const unsigned short* ap = As + (wr * 64 + fr) * 32 + fq * 8;
    const unsigned short* bp = Bs + (wc * 64 + fr) * 32 + fq * 8;
#pragma unroll
    for (int i = 0; i < 4; ++i) {
      af[i]  = *reinterpret_cast<const bf16x8*>(ap + i * 512);
      bfr[i] = *reinterpret_cast<const bf16x8*>(bp + i * 512);
    }
#pragma unroll
    for (int im = 0; im < 4; ++im)
#pragma unroll
      for (int in_ = 0; in_ < 4; ++in_)
        acc[im][in_] = __builtin_amdgcn_mfma_f32_16x16x32_bf16(
            af[im], bfr[in_], acc[im][in_], 0, 0, 0);
  }

  const float inv127 = 1.0f / 127.0f;
#pragma unroll
  for (int in_ = 0; in_ < 4; ++in_) {
    int n = bn * 128 + wc * 64 + in_ * 16 + fr;
    float sc = scales[n] * inv127;
    float bz = bias[n];
#pragma unroll
    for (int im = 0; im < 4; ++im) {
      int m0 = bm * 128 + wr * 64 + im * 16 + fq * 4;
      float* cp = C + (size_t)m0 * NDIM + n;
#pragma unroll
      for (int r = 0; r < 4; ++r)
        cp[(size_t)r * NDIM] = acc[im][in_][r] * sc + bz;
    }
  }
}

// ---------------- host launch ----------------

extern "C" void kernel_launch(void* const* d_in, const int* in_sizes, int n_in,
                              void* d_out, int out_size, void* d_ws, size_t ws_size,
                              hipStream_t stream) {
  const float* x      = (const float*)d_in[0];
  const int*   w8     = (const int*)d_in[1];
  const float* scales = (const float*)d_in[2];
  // d_in[3] = weight_fp : unused by the reference
  const float* bias   = (const float*)d_in[4];
  float* out = (float*)d_out;

  const size_t xb_elems = (size_t)MDIM * KDIM;
  const size_t wb_elems = (size_t)NDIM * KDIM;
  const size_t need = (xb_elems + wb_elems) * sizeof(unsigned short);

  if (ws_size >= need) {
    unsigned short* xb = (unsigned short*)d_ws;
    unsigned short* wb = xb + xb_elems;
    int n8 = (int)(xb_elems / 8);
    cvt_both_kernel<<<2048, 256, 0, stream>>>(x, w8, xb, wb, n8);
    gemm_2bar<<<256, 512, 0, stream>>>(xb, wb, scales, bias, out);
  } else {
    gemm_fused<<<1024, 256, 0, stream>>>(x, w8, scales, bias, out);
  }
}